// Round 12
// baseline (13005.193 us; speedup 1.0000x reference)
//
#include <hip/hip_runtime.h>
#include <stdint.h>

#define NB 1024
#define NT 100
#define NPRED 30
#define NE 512
#define NH 1024
#define NG (3*NH)

typedef unsigned short u16;
typedef unsigned int u32;
typedef u16 u16x4 __attribute__((ext_vector_type(4)));
typedef float f32x4 __attribute__((ext_vector_type(4)));
typedef __bf16 bf16x8 __attribute__((ext_vector_type(8)));

__device__ __forceinline__ u16 f2b(float f){
  u32 u = __float_as_uint(f);
  u = (u + 0x7FFFu + ((u >> 16) & 1u)) >> 16;
  return (u16)u;
}
__device__ __forceinline__ float sig_(float x){ return 1.0f/(1.0f+__expf(-x)); }
__device__ __forceinline__ float tanh_(float x){
  float e = __expf(2.0f*fabsf(x));
  return copysignf(1.0f - 2.0f/(e+1.0f), x);
}

// ---------------- fp32 -> bf16 conversion ----------------
__global__ void cvt_kernel(const float* src, u16* dst, int n4){
  int i = blockIdx.x*256 + threadIdx.x;
  if (i < n4){
    f32x4 v = ((const f32x4*)src)[i];
    u16x4 o;
    o[0]=f2b(v[0]); o[1]=f2b(v[1]); o[2]=f2b(v[2]); o[3]=f2b(v[3]);
    ((u16x4*)dst)[i] = o;
  }
}

// ---------------- standalone first-step embedding ----------------
__global__ void emb_kernel(const float* __restrict__ obs, const float* __restrict__ We,
                           const float* __restrict__ be, u16* __restrict__ out, int t){
  int idx = blockIdx.x*256 + threadIdx.x;      // over NB*NE
  int b = idx >> 9, e = idx & 511;
  float x0 = obs[(b*NT + t)*2], x1 = obs[(b*NT + t)*2 + 1];
  out[idx] = f2b(tanh_(We[e*2]*x0 + We[e*2+1]*x1 + be[e]));
}

// ---------------- async global->LDS (16B per lane) ----------------
__device__ __forceinline__ void gload16(const u16* g, const u16* lds){
  __builtin_amdgcn_global_load_lds(
      (const __attribute__((address_space(1))) void*)g,
      (__attribute__((address_space(3))) void*)lds, 16, 0, 0);
}

// ---------------- 128x128 bf16 GEMM tile ----------------
// W (B-operand): LDS double-buffered, XOR-swizzled (round-5/8 proven path).
// A: NO LDS — per-lane 16B global loads of the MFMA A-fragments, register
//    double-buffered one K-tile ahead (L2-served; A <= 2MB). Cuts LDS traffic
//    per K-tile from 96KB to 48KB — the measured LDS-BW wall (~85 B/cyc b128).
__device__ __forceinline__ void gemm_tile_body(
    const u16* __restrict__ A, int lda,
    const u16* __restrict__ W, int K,
    const float* __restrict__ bias, float* __restrict__ C,
    int bRow, int bCol)
{
  __shared__ __align__(16) u16 Bs[2][128][64];

  const int tid = threadIdx.x;
  const int w = tid >> 6, l = tid & 63;
  const int wm = w >> 1, wn = w & 1;           // 2x2 waves -> 64x64 per wave
  const int fr = l & 15, lhi = l >> 4;         // fragment row, k-group
  const int srow = l >> 3;
  const int gcol = (((l & 7) ^ srow) * 8);     // pre-swizzled W source col (u16)

  f32x4 acc[4][4];
  #pragma unroll
  for (int m=0;m<4;m++)
    #pragma unroll
    for (int n=0;n<4;n++) acc[m][n] = (f32x4)0.0f;

  // A-fragment base for this lane: row = bRow + wm*64 + m*16 + fr, k = lhi*8 (+kk*32)
  const u16* Afrag = A + (size_t)(bRow + wm*64 + fr)*lda + lhi*8;
  const u16* Wb = W + (size_t)bCol*K + gcol;
  const int NK = K >> 6;                       // 8 or 16 (even)

  bf16x8 aA[8], aB[8];                         // [kk*4 + m], two reg banks

  #define PREF_A(ar, kt) do { \
    const u16* _ap = Afrag + (size_t)(kt)*64; \
    _Pragma("unroll") \
    for (int m=0;m<4;m++){ \
      ar[m]     = *(const bf16x8*)(_ap + (size_t)m*16*lda); \
      ar[4 + m] = *(const bf16x8*)(_ap + (size_t)m*16*lda + 32); \
    } } while(0)

  #define STAGE_W(buf, kt) do { int _k0 = (kt)*64; \
    _Pragma("unroll") \
    for (int s4=0;s4<4;s4++){ \
      int slab = w*4 + s4; \
      int row = slab*8 + srow; \
      gload16(Wb + (size_t)row*K + _k0, &Bs[(buf)][slab*8][0]); \
    } } while(0)

  #define COMP(buf, ar) do { \
    _Pragma("unroll") \
    for (int kk=0; kk<2; ++kk){ \
      const int ch = (((kk*4 + lhi) ^ (l & 7)) * 8); \
      bf16x8 bfr[4]; \
      _Pragma("unroll") \
      for (int n=0;n<4;n++) \
        bfr[n] = *(const bf16x8*)(&Bs[(buf)][wn*64 + n*16 + fr][0] + ch); \
      _Pragma("unroll") \
      for (int m=0;m<4;m++) \
        _Pragma("unroll") \
        for (int n=0;n<4;n++) \
          acc[m][n] = __builtin_amdgcn_mfma_f32_16x16x32_bf16(ar[kk*4 + m], bfr[n], acc[m][n], 0, 0, 0); \
    } } while(0)

  PREF_A(aA, 0);
  STAGE_W(0, 0);
  __syncthreads();                             // Bs[0] + aA ready

  for (int t = 0; t < NK; t += 2){
    if (t + 1 < NK) STAGE_W(1, t + 1);
    PREF_A(aB, (t + 1 < NK) ? t + 1 : 0);
    COMP(0, aA);
    __syncthreads();                           // Bs[1] ready, Bs[0] free
    if (t + 2 < NK) STAGE_W(0, t + 2);
    PREF_A(aA, (t + 2 < NK) ? t + 2 : 0);
    COMP(1, aB);
    __syncthreads();                           // Bs[0] ready for next iter
  }

  #undef PREF_A
  #undef STAGE_W
  #undef COMP

  // epilogue: C/D layout col = lane&15, row = (lane>>4)*4 + reg  [m89/m91 verified]
  const int crow = lhi * 4, ccol = l & 15;
  #pragma unroll
  for (int n=0;n<4;n++){
    int col = bCol + wn*64 + n*16 + ccol;
    float bv = bias[col];
    #pragma unroll
    for (int m=0;m<4;m++){
      int row = bRow + wm*64 + m*16 + crow;
      float* Cp = C + (size_t)row*NG + col;
      #pragma unroll
      for (int r=0;r<4;r++)
        __builtin_nontemporal_store(acc[m][n][r] + bv, Cp + (size_t)r*NG);
    }
  }
}

// dual GEMM, flattened 1D grid of 384 with bijective XCD-aware swizzle
__global__ __launch_bounds__(256)
void gemm_dual_kernel(
  const u16* A0, int lda0, int K0, const u16* W0, const float* bias0, float* C0,
  const u16* A1, int lda1, int K1, const u16* W1, const float* bias1, float* C1)
{
  const int id = blockIdx.x;          // 0..383
  const int xcd = id & 7, k = id >> 3;
  const int cb = 3*xcd + (k >> 4);    // 0..23
  const int rem = k & 15;
  const int rb = rem >> 1;            // 0..7
  const int z  = rem & 1;

  if (z == 0)
    gemm_tile_body(A0, lda0, W0, K0, bias0, C0, rb*128, cb*128);
  else
    gemm_tile_body(A1, lda1, W1, K1, bias1, C1, rb*128, cb*128);
}

// ---------------- GRU cell core (block b = batch row b, 256 thr) ----------------
__device__ __forceinline__ void cell_core(
    const float* __restrict__ gx, const float* __restrict__ gh,
    const float* __restrict__ hin, float* __restrict__ hout,
    u16* __restrict__ houtb, u16* __restrict__ seq,
    int b, int jq, f32x4& o)
{
  int idx = b*256 + jq;
  int base = b*768;
  const f32x4* gx4 = (const f32x4*)gx;
  const f32x4* gh4 = (const f32x4*)gh;
  f32x4 xr = gx4[base + jq], xz = gx4[base + 256 + jq], xn = gx4[base + 512 + jq];
  f32x4 hr = gh4[base + jq], hz = gh4[base + 256 + jq], hn = gh4[base + 512 + jq];
  f32x4 hv = ((const f32x4*)hin)[idx];
  u16x4 ob;
  #pragma unroll
  for (int c=0;c<4;c++){
    float r = sig_(xr[c] + hr[c]);
    float z = sig_(xz[c] + hz[c]);
    float n = tanh_(xn[c] + r*hn[c]);
    float h = (1.0f - z)*n + z*hv[c];
    o[c] = h; ob[c] = f2b(h);
  }
  ((f32x4*)hout)[idx] = o;
  ((u16x4*)houtb)[idx] = ob;
  if (seq) ((u16x4*)seq)[idx] = ob;
}

// plain cell
__global__ void gru_cell_kernel(const float* __restrict__ gx, const float* __restrict__ gh,
                                const float* __restrict__ hin, float* __restrict__ hout,
                                u16* __restrict__ houtb, u16* __restrict__ seq)
{
  f32x4 o;
  cell_core(gx, gh, hin, hout, houtb, seq, blockIdx.x, threadIdx.x, o);
}

// cell + fused next-step input embedding (encoder)
__global__ void gru_cell_emb_kernel(const float* __restrict__ gx, const float* __restrict__ gh,
                                    const float* __restrict__ hin, float* __restrict__ hout,
                                    u16* __restrict__ houtb, u16* __restrict__ seq,
                                    const float* __restrict__ obs, const float* __restrict__ We,
                                    const float* __restrict__ be, u16* __restrict__ embb, int et)
{
  int b = blockIdx.x, tid = threadIdx.x;
  f32x4 o;
  cell_core(gx, gh, hin, hout, houtb, seq, b, tid, o);
  if (embb){
    float x0 = obs[(b*NT + et)*2], x1 = obs[(b*NT + et)*2 + 1];
    int e0 = tid*2;
    u16 v0 = f2b(tanh_(We[e0*2]  *x0 + We[e0*2+1]*x1 + be[e0]));
    u16 v1 = f2b(tanh_(We[e0*2+2]*x0 + We[e0*2+3]*x1 + be[e0+1]));
    ((u32*)embb)[b*256 + tid] = (u32)v0 | ((u32)v1 << 16);
  }
}

// cell + fused output projection + fused decoder embedding
__global__ void gru_cell_out_kernel(const float* __restrict__ gx, const float* __restrict__ gh,
                                    const float* __restrict__ hin, float* __restrict__ hout,
                                    u16* __restrict__ houtb,
                                    const float* __restrict__ Wout, const float* __restrict__ bout,
                                    float* __restrict__ dout, int ot,
                                    const float* __restrict__ Wed, const float* __restrict__ bed,
                                    u16* __restrict__ dembb)
{
  int b = blockIdx.x, tid = threadIdx.x;
  f32x4 o;
  cell_core(gx, gh, hin, hout, houtb, (u16*)nullptr, b, tid, o);

  // outproj: s = h[b,:] . Wout  (block-local reduction)
  int j0 = tid*4;
  float s0 = 0.f, s1 = 0.f;
  #pragma unroll
  for (int c=0;c<4;c++){
    s0 += o[c]*Wout[j0+c];
    s1 += o[c]*Wout[NH + j0 + c];
  }
  #pragma unroll
  for (int off = 32; off > 0; off >>= 1){
    s0 += __shfl_down(s0, off);
    s1 += __shfl_down(s1, off);
  }
  __shared__ float red[8];
  __shared__ float lastsh[2];
  int w = tid >> 6;
  if ((tid & 63) == 0){ red[w*2] = s0; red[w*2+1] = s1; }
  __syncthreads();
  if (tid == 0){
    float o0 = red[0]+red[2]+red[4]+red[6] + bout[0];
    float o1 = red[1]+red[3]+red[5]+red[7] + bout[1];
    lastsh[0] = o0; lastsh[1] = o1;
    if (dout){ dout[(size_t)b*(NPRED*2) + ot*2]     = o0;
               dout[(size_t)b*(NPRED*2) + ot*2 + 1] = o1; }
  }
  __syncthreads();
  // demb: dembb[b, e] = tanh(Wed[e,:] . last + bed[e])
  float x0 = lastsh[0], x1 = lastsh[1];
  int e0 = tid*2;
  u16 v0 = f2b(tanh_(Wed[e0*2]  *x0 + Wed[e0*2+1]*x1 + bed[e0]));
  u16 v1 = f2b(tanh_(Wed[e0*2+2]*x0 + Wed[e0*2+3]*x1 + bed[e0+1]));
  ((u32*)dembb)[b*256 + tid] = (u32)v0 | ((u32)v1 << 16);
}

extern "C" void kernel_launch(void* const* d_in, const int* in_sizes, int n_in,
                              void* d_out, int out_size, void* d_ws, size_t ws_size,
                              hipStream_t stream)
{
  (void)in_sizes; (void)n_in; (void)out_size;
  const float* obs  = (const float*)d_in[0];
  const float* We   = (const float*)d_in[1];
  const float* be   = (const float*)d_in[2];
  const float* Wed  = (const float*)d_in[3];
  const float* bed  = (const float*)d_in[4];
  const float* e1Wih = (const float*)d_in[5];
  const float* e1Whh = (const float*)d_in[6];
  const float* e1bih = (const float*)d_in[7];
  const float* e1bhh = (const float*)d_in[8];
  const float* e2Wih = (const float*)d_in[9];
  const float* e2Whh = (const float*)d_in[10];
  const float* e2bih = (const float*)d_in[11];
  const float* e2bhh = (const float*)d_in[12];
  const float* d1Wih = (const float*)d_in[13];
  const float* d1Whh = (const float*)d_in[14];
  const float* d1bih = (const float*)d_in[15];
  const float* d1bhh = (const float*)d_in[16];
  const float* d2Wih = (const float*)d_in[17];
  const float* d2Whh = (const float*)d_in[18];
  const float* d2bih = (const float*)d_in[19];
  const float* d2bhh = (const float*)d_in[20];
  const float* Wout = (const float*)d_in[21];
  const float* bout = (const float*)d_in[22];
  float* out = (float*)d_out;

  // ---- ws-adaptive workspace layout ----
  char* ws = (char*)d_ws;
  size_t off = 0;
  auto alloc = [&](size_t bytes)->char* {
    char* p = ws + off;
    off += (bytes + 255) & ~(size_t)255;
    return p;
  };
  u16* wE1i = (u16*)alloc((size_t)NG*NE*2);
  u16* wE1h = (u16*)alloc((size_t)NG*NH*2);
  u16* wE2i = (u16*)alloc((size_t)NG*NH*2);
  u16* wE2h = (u16*)alloc((size_t)NG*NH*2);
  u16* wD1i = (u16*)alloc((size_t)NG*NE*2);
  u16* wD1h = (u16*)alloc((size_t)NG*NH*2);
  u16* wD2i = (u16*)alloc((size_t)NG*NH*2);
  u16* wD2h = (u16*)alloc((size_t)NG*NH*2);
  u16* embb  = (u16*)alloc((size_t)NB*NE*2);
  u16* dembb = (u16*)alloc((size_t)NB*NE*2);
  float* h1f = (float*)alloc((size_t)NB*NH*4);
  u16*   h1b = (u16*)alloc((size_t)NB*NH*2);
  float* h2f = (float*)alloc((size_t)NB*NH*4);
  u16*   h2b = (u16*)alloc((size_t)NB*NH*2);
  float* gx  = (float*)alloc((size_t)NB*NG*4);
  float* gh  = (float*)alloc((size_t)NB*NG*4);

  // enc1 cache: as many TRAILING steps as fit; prefix recomputed in pass 2.
  const size_t slot = (size_t)NB*NH*2;     // 2 MB/step
  size_t avail = (ws_size > off + (1u<<20)) ? (ws_size - off - (1u<<20)) : 0;
  int cs = (int)(avail / slot);
  if (cs > NT) cs = NT;
  u16* cache = (u16*)alloc((size_t)cs * slot);
  const int cache_start = NT - cs;

  // ---- init ----
  hipMemsetAsync(h1f, 0, (size_t)NB*NH*4, stream);
  hipMemsetAsync(h1b, 0, (size_t)NB*NH*2, stream);

  auto cvt = [&](const float* src, u16* dst, size_t n){
    int n4 = (int)(n >> 2);
    cvt_kernel<<<dim3((n4 + 255)/256), dim3(256), 0, stream>>>(src, dst, n4);
  };
  cvt(e1Wih, wE1i, (size_t)NG*NE);
  cvt(e1Whh, wE1h, (size_t)NG*NH);
  cvt(e2Wih, wE2i, (size_t)NG*NH);
  cvt(e2Whh, wE2h, (size_t)NG*NH);
  cvt(d1Wih, wD1i, (size_t)NG*NE);
  cvt(d1Whh, wD1h, (size_t)NG*NH);
  cvt(d2Wih, wD2i, (size_t)NG*NH);
  cvt(d2Whh, wD2h, (size_t)NG*NH);

  const dim3 blk(256);
  const dim3 dual_grid(384);                 // flattened, XCD-swizzled
  const dim3 emb_grid((NB*NE)/256);          // 2048
  const dim3 cell_grid(NB);                  // block = batch row

  // ---- pass 1: GRU1 over all T (stores trailing cs outputs; emb fused) ----
  emb_kernel<<<emb_grid, blk, 0, stream>>>(obs, We, be, embb, 0);
  for (int t = 0; t < NT; ++t){
    gemm_dual_kernel<<<dual_grid, blk, 0, stream>>>(
        embb, NE, NE, wE1i, e1bih, gx,
        h1b,  NH, NH, wE1h, e1bhh, gh);
    u16* slot_p = (t >= cache_start) ? cache + (size_t)(t - cache_start)*NB*NH : (u16*)nullptr;
    gru_cell_emb_kernel<<<cell_grid, blk, 0, stream>>>(
        gx, gh, h1f, h1f, h1b, slot_p,
        obs, We, be, (t+1 < NT) ? embb : (u16*)nullptr, t+1);
  }

  // GRU2 initial hidden = GRU1 final hidden (the reference quirk)
  hipMemcpyAsync(h2f, h1f, (size_t)NB*NH*4, hipMemcpyDeviceToDevice, stream);
  hipMemcpyAsync(h2b, h1b, (size_t)NB*NH*2, hipMemcpyDeviceToDevice, stream);

  // ---- pass 2: GRU2 over all T; recompute GRU1 prefix where not cached ----
  if (cache_start > 0){
    hipMemsetAsync(h1f, 0, (size_t)NB*NH*4, stream);
    hipMemsetAsync(h1b, 0, (size_t)NB*NH*2, stream);
    emb_kernel<<<emb_grid, blk, 0, stream>>>(obs, We, be, embb, 0);
  }
  for (int t = 0; t < cache_start; ++t){
    gemm_dual_kernel<<<dual_grid, blk, 0, stream>>>(
        embb, NE, NE, wE1i, e1bih, gx,
        h1b,  NH, NH, wE1h, e1bhh, gh);
    gru_cell_emb_kernel<<<cell_grid, blk, 0, stream>>>(
        gx, gh, h1f, h1f, h1b, (u16*)nullptr,
        obs, We, be, (t+1 < cache_start) ? embb : (u16*)nullptr, t+1);
    gemm_dual_kernel<<<dual_grid, blk, 0, stream>>>(
        h1b, NH, NH, wE2i, e2bih, gx,
        h2b, NH, NH, wE2h, e2bhh, gh);
    if (t == NT - 2)
      gru_cell_out_kernel<<<cell_grid, blk, 0, stream>>>(
          gx, gh, h2f, h2f, h2b, Wout, bout, (float*)nullptr, 0, Wed, bed, dembb);
    else
      gru_cell_kernel<<<cell_grid, blk, 0, stream>>>(gx, gh, h2f, h2f, h2b, (u16*)nullptr);
  }
  for (int t = cache_start; t < NT; ++t){
    const u16* enc1_t = cache + (size_t)(t - cache_start)*NB*NH;
    gemm_dual_kernel<<<dual_grid, blk, 0, stream>>>(
        enc1_t, NH, NH, wE2i, e2bih, gx,
        h2b,    NH, NH, wE2h, e2bhh, gh);
    if (t == NT - 2)
      gru_cell_out_kernel<<<cell_grid, blk, 0, stream>>>(
          gx, gh, h2f, h2f, h2b, Wout, bout, (float*)nullptr, 0, Wed, bed, dembb);
    else
      gru_cell_kernel<<<cell_grid, blk, 0, stream>>>(gx, gh, h2f, h2f, h2b, (u16*)nullptr);
  }

  // ---- autoregressive decoder (carry = h2, intermediate = h1) ----
  for (int t = 0; t < NPRED; ++t){
    gemm_dual_kernel<<<dual_grid, blk, 0, stream>>>(
        dembb, NE, NE, wD1i, d1bih, gx,
        h2b,   NH, NH, wD1h, d1bhh, gh);
    gru_cell_kernel<<<cell_grid, blk, 0, stream>>>(gx, gh, h2f, h1f, h1b, (u16*)nullptr);
    gemm_dual_kernel<<<dual_grid, blk, 0, stream>>>(
        h1b, NH, NH, wD2i, d2bih, gx,
        h1b, NH, NH, wD2h, d2bhh, gh);
    gru_cell_out_kernel<<<cell_grid, blk, 0, stream>>>(
        gx, gh, h1f, h2f, h2b, Wout, bout, out, t, Wed, bed, dembb);
  }
}

// Round 13
// 8206.188 us; speedup vs baseline: 1.5848x; 1.5848x over previous
//
#include <hip/hip_runtime.h>
#include <stdint.h>

#define NB 1024
#define NT 100
#define NPRED 30
#define NE 512
#define NH 1024
#define NG (3*NH)

typedef unsigned short u16;
typedef unsigned int u32;
typedef u16 u16x4 __attribute__((ext_vector_type(4)));
typedef float f32x4 __attribute__((ext_vector_type(4)));
typedef __bf16 bf16x8 __attribute__((ext_vector_type(8)));

__device__ __forceinline__ u16 f2b(float f){
  u32 u = __float_as_uint(f);
  u = (u + 0x7FFFu + ((u >> 16) & 1u)) >> 16;
  return (u16)u;
}
__device__ __forceinline__ float sig_(float x){ return 1.0f/(1.0f+__expf(-x)); }
__device__ __forceinline__ float tanh_(float x){
  float e = __expf(2.0f*fabsf(x));
  return copysignf(1.0f - 2.0f/(e+1.0f), x);
}

// ---------------- fp32 -> bf16 conversion ----------------
__global__ void cvt_kernel(const float* src, u16* dst, int n4){
  int i = blockIdx.x*256 + threadIdx.x;
  if (i < n4){
    f32x4 v = ((const f32x4*)src)[i];
    u16x4 o;
    o[0]=f2b(v[0]); o[1]=f2b(v[1]); o[2]=f2b(v[2]); o[3]=f2b(v[3]);
    ((u16x4*)dst)[i] = o;
  }
}

// ---------------- standalone first-step embedding ----------------
__global__ void emb_kernel(const float* __restrict__ obs, const float* __restrict__ We,
                           const float* __restrict__ be, u16* __restrict__ out, int t){
  int idx = blockIdx.x*256 + threadIdx.x;      // over NB*NE
  int b = idx >> 9, e = idx & 511;
  float x0 = obs[(b*NT + t)*2], x1 = obs[(b*NT + t)*2 + 1];
  out[idx] = f2b(tanh_(We[e*2]*x0 + We[e*2+1]*x1 + be[e]));
}

// ---------------- async global->LDS (16B per lane) ----------------
__device__ __forceinline__ void gload16(const u16* g, const u16* lds){
  __builtin_amdgcn_global_load_lds(
      (const __attribute__((address_space(1))) void*)g,
      (__attribute__((address_space(3))) void*)lds, 16, 0, 0);
}

// ---------------- 128x128 bf16 GEMM tile, BK=64, dbuf LDS, XOR-swizzled ----------------
// (round-5/7/8 proven body). LDS(row, chunk16B) holds global(row, chunk ^ (row&7)).
__device__ __forceinline__ void gemm_tile_body(
    const u16* __restrict__ A, int lda,
    const u16* __restrict__ W, int K,
    const float* __restrict__ bias, float* __restrict__ C,
    int bRow, int bCol)
{
  __shared__ __align__(16) u16 As[2][128][64];
  __shared__ __align__(16) u16 Bs[2][128][64];

  const int tid = threadIdx.x;
  const int w = tid >> 6, l = tid & 63;
  const int wm = w >> 1, wn = w & 1;           // 2x2 waves -> 64x64 per wave
  const int fr = l & 15, lhi = l >> 4;         // fragment row, k-group
  const int srow = l >> 3;
  const int gcol = (((l & 7) ^ srow) * 8);     // pre-swizzled source col (u16)

  f32x4 acc[4][4];
  #pragma unroll
  for (int m=0;m<4;m++)
    #pragma unroll
    for (int n=0;n<4;n++) acc[m][n] = (f32x4)0.0f;

  const u16* Ab = A + (size_t)bRow*lda + gcol;
  const u16* Wb = W + (size_t)bCol*K + gcol;
  const int NK = K >> 6;

  #pragma unroll
  for (int s4=0;s4<4;s4++){
    int slab = w*4 + s4;
    int row = slab*8 + srow;
    gload16(Ab + (size_t)row*lda, &As[0][slab*8][0]);
    gload16(Wb + (size_t)row*K,   &Bs[0][slab*8][0]);
  }
  __syncthreads();

  for (int t = 0; t < NK; ++t){
    const int cur = t & 1;
    if (t + 1 < NK){
      const int k0 = (t+1)*64;
      #pragma unroll
      for (int s4=0;s4<4;s4++){
        int slab = w*4 + s4;
        int row = slab*8 + srow;
        gload16(Ab + (size_t)row*lda + k0, &As[cur^1][slab*8][0]);
        gload16(Wb + (size_t)row*K   + k0, &Bs[cur^1][slab*8][0]);
      }
    }
    const u16* Ac = &As[cur][0][0];
    const u16* Bc = &Bs[cur][0][0];
    #pragma unroll
    for (int kk=0; kk<2; ++kk){
      const int ch = (((kk*4 + lhi) ^ (l & 7)) * 8);   // swizzled 16B chunk
      bf16x8 af[4], bfr[4];
      #pragma unroll
      for (int m=0;m<4;m++)
        af[m] = *(const bf16x8*)(Ac + (size_t)(wm*64 + m*16 + fr)*64 + ch);
      #pragma unroll
      for (int n=0;n<4;n++)
        bfr[n] = *(const bf16x8*)(Bc + (size_t)(wn*64 + n*16 + fr)*64 + ch);
      #pragma unroll
      for (int m=0;m<4;m++)
        #pragma unroll
        for (int n=0;n<4;n++)
          acc[m][n] = __builtin_amdgcn_mfma_f32_16x16x32_bf16(af[m], bfr[n], acc[m][n], 0, 0, 0);
    }
    __syncthreads();
  }

  // epilogue: C/D layout col = lane&15, row = (lane>>4)*4 + reg  [m89/m91 verified]
  const int crow = lhi * 4, ccol = l & 15;
  #pragma unroll
  for (int n=0;n<4;n++){
    int col = bCol + wn*64 + n*16 + ccol;
    float bv = bias[col];
    #pragma unroll
    for (int m=0;m<4;m++){
      int row = bRow + wm*64 + m*16 + crow;
      float* Cp = C + (size_t)row*NG + col;
      #pragma unroll
      for (int r=0;r<4;r++)
        __builtin_nontemporal_store(acc[m][n][r] + bv, Cp + (size_t)r*NG);
    }
  }
}

// dual GEMM, flattened 1D grid of 384 with bijective XCD-aware swizzle
__global__ __launch_bounds__(256)
void gemm_dual_kernel(
  const u16* A0, int lda0, int K0, const u16* W0, const float* bias0, float* C0,
  const u16* A1, int lda1, int K1, const u16* W1, const float* bias1, float* C1)
{
  const int id = blockIdx.x;          // 0..383
  const int xcd = id & 7, k = id >> 3;
  const int cb = 3*xcd + (k >> 4);    // 0..23
  const int rem = k & 15;
  const int rb = rem >> 1;            // 0..7
  const int z  = rem & 1;

  if (z == 0)
    gemm_tile_body(A0, lda0, W0, K0, bias0, C0, rb*128, cb*128);
  else
    gemm_tile_body(A1, lda1, W1, K1, bias1, C1, rb*128, cb*128);
}

// ---------------- GRU cell core (block b = batch row b, 256 thr) ----------------
__device__ __forceinline__ void cell_core(
    const float* __restrict__ gx, const float* __restrict__ gh,
    const float* __restrict__ hin, float* __restrict__ hout,
    u16* __restrict__ houtb, u16* __restrict__ seq,
    int b, int jq, f32x4& o)
{
  int idx = b*256 + jq;
  int base = b*768;
  const f32x4* gx4 = (const f32x4*)gx;
  const f32x4* gh4 = (const f32x4*)gh;
  f32x4 xr = gx4[base + jq], xz = gx4[base + 256 + jq], xn = gx4[base + 512 + jq];
  f32x4 hr = gh4[base + jq], hz = gh4[base + 256 + jq], hn = gh4[base + 512 + jq];
  f32x4 hv = ((const f32x4*)hin)[idx];
  u16x4 ob;
  #pragma unroll
  for (int c=0;c<4;c++){
    float r = sig_(xr[c] + hr[c]);
    float z = sig_(xz[c] + hz[c]);
    float n = tanh_(xn[c] + r*hn[c]);
    float h = (1.0f - z)*n + z*hv[c];
    o[c] = h; ob[c] = f2b(h);
  }
  ((f32x4*)hout)[idx] = o;
  ((u16x4*)houtb)[idx] = ob;
  if (seq) ((u16x4*)seq)[idx] = ob;
}

// plain cell
__global__ void gru_cell_kernel(const float* __restrict__ gx, const float* __restrict__ gh,
                                const float* __restrict__ hin, float* __restrict__ hout,
                                u16* __restrict__ houtb, u16* __restrict__ seq)
{
  f32x4 o;
  cell_core(gx, gh, hin, hout, houtb, seq, blockIdx.x, threadIdx.x, o);
}

// cell + fused next-step input embedding (encoder)
__global__ void gru_cell_emb_kernel(const float* __restrict__ gx, const float* __restrict__ gh,
                                    const float* __restrict__ hin, float* __restrict__ hout,
                                    u16* __restrict__ houtb, u16* __restrict__ seq,
                                    const float* __restrict__ obs, const float* __restrict__ We,
                                    const float* __restrict__ be, u16* __restrict__ embb, int et)
{
  int b = blockIdx.x, tid = threadIdx.x;
  f32x4 o;
  cell_core(gx, gh, hin, hout, houtb, seq, b, tid, o);
  if (embb){
    float x0 = obs[(b*NT + et)*2], x1 = obs[(b*NT + et)*2 + 1];
    int e0 = tid*2;
    u16 v0 = f2b(tanh_(We[e0*2]  *x0 + We[e0*2+1]*x1 + be[e0]));
    u16 v1 = f2b(tanh_(We[e0*2+2]*x0 + We[e0*2+3]*x1 + be[e0+1]));
    ((u32*)embb)[b*256 + tid] = (u32)v0 | ((u32)v1 << 16);
  }
}

// cell + fused output projection + fused decoder embedding
__global__ void gru_cell_out_kernel(const float* __restrict__ gx, const float* __restrict__ gh,
                                    const float* __restrict__ hin, float* __restrict__ hout,
                                    u16* __restrict__ houtb,
                                    const float* __restrict__ Wout, const float* __restrict__ bout,
                                    float* __restrict__ dout, int ot,
                                    const float* __restrict__ Wed, const float* __restrict__ bed,
                                    u16* __restrict__ dembb)
{
  int b = blockIdx.x, tid = threadIdx.x;
  f32x4 o;
  cell_core(gx, gh, hin, hout, houtb, (u16*)nullptr, b, tid, o);

  // outproj: s = h[b,:] . Wout  (block-local reduction)
  int j0 = tid*4;
  float s0 = 0.f, s1 = 0.f;
  #pragma unroll
  for (int c=0;c<4;c++){
    s0 += o[c]*Wout[j0+c];
    s1 += o[c]*Wout[NH + j0 + c];
  }
  #pragma unroll
  for (int off = 32; off > 0; off >>= 1){
    s0 += __shfl_down(s0, off);
    s1 += __shfl_down(s1, off);
  }
  __shared__ float red[8];
  __shared__ float lastsh[2];
  int w = tid >> 6;
  if ((tid & 63) == 0){ red[w*2] = s0; red[w*2+1] = s1; }
  __syncthreads();
  if (tid == 0){
    float o0 = red[0]+red[2]+red[4]+red[6] + bout[0];
    float o1 = red[1]+red[3]+red[5]+red[7] + bout[1];
    lastsh[0] = o0; lastsh[1] = o1;
    if (dout){ dout[(size_t)b*(NPRED*2) + ot*2]     = o0;
               dout[(size_t)b*(NPRED*2) + ot*2 + 1] = o1; }
  }
  __syncthreads();
  // demb: dembb[b, e] = tanh(Wed[e,:] . last + bed[e])
  float x0 = lastsh[0], x1 = lastsh[1];
  int e0 = tid*2;
  u16 v0 = f2b(tanh_(Wed[e0*2]  *x0 + Wed[e0*2+1]*x1 + bed[e0]));
  u16 v1 = f2b(tanh_(Wed[e0*2+2]*x0 + Wed[e0*2+3]*x1 + bed[e0+1]));
  ((u32*)dembb)[b*256 + tid] = (u32)v0 | ((u32)v1 << 16);
}

extern "C" void kernel_launch(void* const* d_in, const int* in_sizes, int n_in,
                              void* d_out, int out_size, void* d_ws, size_t ws_size,
                              hipStream_t stream)
{
  (void)in_sizes; (void)n_in; (void)out_size;
  const float* obs  = (const float*)d_in[0];
  const float* We   = (const float*)d_in[1];
  const float* be   = (const float*)d_in[2];
  const float* Wed  = (const float*)d_in[3];
  const float* bed  = (const float*)d_in[4];
  const float* e1Wih = (const float*)d_in[5];
  const float* e1Whh = (const float*)d_in[6];
  const float* e1bih = (const float*)d_in[7];
  const float* e1bhh = (const float*)d_in[8];
  const float* e2Wih = (const float*)d_in[9];
  const float* e2Whh = (const float*)d_in[10];
  const float* e2bih = (const float*)d_in[11];
  const float* e2bhh = (const float*)d_in[12];
  const float* d1Wih = (const float*)d_in[13];
  const float* d1Whh = (const float*)d_in[14];
  const float* d1bih = (const float*)d_in[15];
  const float* d1bhh = (const float*)d_in[16];
  const float* d2Wih = (const float*)d_in[17];
  const float* d2Whh = (const float*)d_in[18];
  const float* d2bih = (const float*)d_in[19];
  const float* d2bhh = (const float*)d_in[20];
  const float* Wout = (const float*)d_in[21];
  const float* bout = (const float*)d_in[22];
  float* out = (float*)d_out;

  // ---- ws-adaptive workspace layout ----
  char* ws = (char*)d_ws;
  size_t off = 0;
  auto alloc = [&](size_t bytes)->char* {
    char* p = ws + off;
    off += (bytes + 255) & ~(size_t)255;
    return p;
  };
  u16* wE1i = (u16*)alloc((size_t)NG*NE*2);
  u16* wE1h = (u16*)alloc((size_t)NG*NH*2);
  u16* wE2i = (u16*)alloc((size_t)NG*NH*2);
  u16* wE2h = (u16*)alloc((size_t)NG*NH*2);
  u16* wD1i = (u16*)alloc((size_t)NG*NE*2);
  u16* wD1h = (u16*)alloc((size_t)NG*NH*2);
  u16* wD2i = (u16*)alloc((size_t)NG*NH*2);
  u16* wD2h = (u16*)alloc((size_t)NG*NH*2);
  u16* embb  = (u16*)alloc((size_t)NB*NE*2);
  u16* dembb = (u16*)alloc((size_t)NB*NE*2);
  float* h1f = (float*)alloc((size_t)NB*NH*4);
  u16*   h1b = (u16*)alloc((size_t)NB*NH*2);
  float* h2f = (float*)alloc((size_t)NB*NH*4);
  u16*   h2b = (u16*)alloc((size_t)NB*NH*2);
  float* gx  = (float*)alloc((size_t)NB*NG*4);
  float* gh  = (float*)alloc((size_t)NB*NG*4);

  // enc1 cache: as many TRAILING steps as fit; prefix recomputed in pass 2.
  const size_t slot = (size_t)NB*NH*2;     // 2 MB/step
  size_t avail = (ws_size > off + (1u<<20)) ? (ws_size - off - (1u<<20)) : 0;
  int cs = (int)(avail / slot);
  if (cs > NT) cs = NT;
  u16* cache = (u16*)alloc((size_t)cs * slot);
  const int cache_start = NT - cs;

  // ---- init ----
  hipMemsetAsync(h1f, 0, (size_t)NB*NH*4, stream);
  hipMemsetAsync(h1b, 0, (size_t)NB*NH*2, stream);

  auto cvt = [&](const float* src, u16* dst, size_t n){
    int n4 = (int)(n >> 2);
    cvt_kernel<<<dim3((n4 + 255)/256), dim3(256), 0, stream>>>(src, dst, n4);
  };
  cvt(e1Wih, wE1i, (size_t)NG*NE);
  cvt(e1Whh, wE1h, (size_t)NG*NH);
  cvt(e2Wih, wE2i, (size_t)NG*NH);
  cvt(e2Whh, wE2h, (size_t)NG*NH);
  cvt(d1Wih, wD1i, (size_t)NG*NE);
  cvt(d1Whh, wD1h, (size_t)NG*NH);
  cvt(d2Wih, wD2i, (size_t)NG*NH);
  cvt(d2Whh, wD2h, (size_t)NG*NH);

  const dim3 blk(256);
  const dim3 dual_grid(384);                 // flattened, XCD-swizzled
  const dim3 emb_grid((NB*NE)/256);          // 2048
  const dim3 cell_grid(NB);                  // block = batch row

  // ---- pass 1: GRU1 over all T (stores trailing cs outputs; emb fused) ----
  emb_kernel<<<emb_grid, blk, 0, stream>>>(obs, We, be, embb, 0);
  for (int t = 0; t < NT; ++t){
    gemm_dual_kernel<<<dual_grid, blk, 0, stream>>>(
        embb, NE, NE, wE1i, e1bih, gx,
        h1b,  NH, NH, wE1h, e1bhh, gh);
    u16* slot_p = (t >= cache_start) ? cache + (size_t)(t - cache_start)*NB*NH : (u16*)nullptr;
    gru_cell_emb_kernel<<<cell_grid, blk, 0, stream>>>(
        gx, gh, h1f, h1f, h1b, slot_p,
        obs, We, be, (t+1 < NT) ? embb : (u16*)nullptr, t+1);
  }

  // GRU2 initial hidden = GRU1 final hidden (the reference quirk)
  hipMemcpyAsync(h2f, h1f, (size_t)NB*NH*4, hipMemcpyDeviceToDevice, stream);
  hipMemcpyAsync(h2b, h1b, (size_t)NB*NH*2, hipMemcpyDeviceToDevice, stream);

  // ---- pass 2: GRU2 over all T; recompute GRU1 prefix where not cached ----
  if (cache_start > 0){
    hipMemsetAsync(h1f, 0, (size_t)NB*NH*4, stream);
    hipMemsetAsync(h1b, 0, (size_t)NB*NH*2, stream);
    emb_kernel<<<emb_grid, blk, 0, stream>>>(obs, We, be, embb, 0);
  }
  for (int t = 0; t < cache_start; ++t){
    gemm_dual_kernel<<<dual_grid, blk, 0, stream>>>(
        embb, NE, NE, wE1i, e1bih, gx,
        h1b,  NH, NH, wE1h, e1bhh, gh);
    gru_cell_emb_kernel<<<cell_grid, blk, 0, stream>>>(
        gx, gh, h1f, h1f, h1b, (u16*)nullptr,
        obs, We, be, (t+1 < cache_start) ? embb : (u16*)nullptr, t+1);
    gemm_dual_kernel<<<dual_grid, blk, 0, stream>>>(
        h1b, NH, NH, wE2i, e2bih, gx,
        h2b, NH, NH, wE2h, e2bhh, gh);
    if (t == NT - 2)
      gru_cell_out_kernel<<<cell_grid, blk, 0, stream>>>(
          gx, gh, h2f, h2f, h2b, Wout, bout, (float*)nullptr, 0, Wed, bed, dembb);
    else
      gru_cell_kernel<<<cell_grid, blk, 0, stream>>>(gx, gh, h2f, h2f, h2b, (u16*)nullptr);
  }
  for (int t = cache_start; t < NT; ++t){
    const u16* enc1_t = cache + (size_t)(t - cache_start)*NB*NH;
    gemm_dual_kernel<<<dual_grid, blk, 0, stream>>>(
        enc1_t, NH, NH, wE2i, e2bih, gx,
        h2b,    NH, NH, wE2h, e2bhh, gh);
    if (t == NT - 2)
      gru_cell_out_kernel<<<cell_grid, blk, 0, stream>>>(
          gx, gh, h2f, h2f, h2b, Wout, bout, (float*)nullptr, 0, Wed, bed, dembb);
    else
      gru_cell_kernel<<<cell_grid, blk, 0, stream>>>(gx, gh, h2f, h2f, h2b, (u16*)nullptr);
  }

  // ---- autoregressive decoder (carry = h2, intermediate = h1) ----
  for (int t = 0; t < NPRED; ++t){
    gemm_dual_kernel<<<dual_grid, blk, 0, stream>>>(
        dembb, NE, NE, wD1i, d1bih, gx,
        h2b,   NH, NH, wD1h, d1bhh, gh);
    gru_cell_kernel<<<cell_grid, blk, 0, stream>>>(gx, gh, h2f, h1f, h1b, (u16*)nullptr);
    gemm_dual_kernel<<<dual_grid, blk, 0, stream>>>(
        h1b, NH, NH, wD2i, d2bih, gx,
        h1b, NH, NH, wD2h, d2bhh, gh);
    gru_cell_out_kernel<<<cell_grid, blk, 0, stream>>>(
        gx, gh, h1f, h2f, h2b, Wout, bout, out, t, Wed, bed, dembb);
  }
}